// Round 1
// baseline (2598.276 us; speedup 1.0000x reference)
//
#include <hip/hip_runtime.h>
#include <math.h>

#define NB    8
#define CDIM  256
#define NN    2304
#define NH    4
#define DH    32
#define HIDC  128
#define OC3   384
#define QK_SCALE 0.17677669529663687f   // 32^-0.5

// ---------------------------------------------------------------------------
// Kernel 1: QKV projection.  qkv[b][o][n] = sum_k w_qkv[o][k] * x[b][k][n]
// Written transposed into q_t/k_t/v_t as [b*NH+h][n][d] (q pre-scaled by
// QK_SCALE) so the attention kernel reads K/V rows at wave-uniform addresses.
// 64x64 tile, K-tiles of 16, 4x4 register tile per thread, float4 LDS reads.
// ---------------------------------------------------------------------------
__global__ __launch_bounds__(256) void qkv_proj_kernel(
    const float* __restrict__ x, const float* __restrict__ w,
    float* __restrict__ qt, float* __restrict__ kt, float* __restrict__ vt)
{
    __shared__ float Ws[16][68];   // [k][o], pad 68 keeps float4 alignment
    __shared__ float Xs[16][68];   // [k][n]
    const int n0 = blockIdx.x * 64;
    const int o0 = blockIdx.y * 64;
    const int b  = blockIdx.z;
    const int tid = (int)threadIdx.x;
    const int tm = tid >> 4;        // o-subtile 0..15
    const int tn = tid & 15;        // n-subtile 0..15
    const float* xb = x + (size_t)b * CDIM * NN;

    float acc[4][4];
#pragma unroll
    for (int i = 0; i < 4; ++i)
#pragma unroll
        for (int j = 0; j < 4; ++j) acc[i][j] = 0.f;

    const int lo  = tid >> 4;        // o lane for W load
    const int lk  = tid & 15;        // k lane for W load
    const int xn  = tid & 63;        // n lane for X load
    const int xk4 = (tid >> 6) * 4;  // k base for X load

    for (int k0 = 0; k0 < CDIM; k0 += 16) {
#pragma unroll
        for (int r = 0; r < 4; ++r) {
            const int o = lo + 16 * r;
            Ws[lk][o] = w[(size_t)(o0 + o) * CDIM + (k0 + lk)];
        }
#pragma unroll
        for (int r = 0; r < 4; ++r) {
            const int k = xk4 + r;
            Xs[k][xn] = xb[(size_t)(k0 + k) * NN + (n0 + xn)];
        }
        __syncthreads();
#pragma unroll
        for (int k = 0; k < 16; ++k) {
            const float4 av = *(const float4*)&Ws[k][tm * 4];
            const float4 bv = *(const float4*)&Xs[k][tn * 4];
            const float a[4]  = {av.x, av.y, av.z, av.w};
            const float bb[4] = {bv.x, bv.y, bv.z, bv.w};
#pragma unroll
            for (int i = 0; i < 4; ++i)
#pragma unroll
                for (int j = 0; j < 4; ++j)
                    acc[i][j] += a[i] * bb[j];
        }
        __syncthreads();
    }

    // Transposed store: o -> (sel, h, d); thread's 4 o's are 4 consecutive d.
    const int obase = o0 + tm * 4;
    const int sel = obase >> 7;            // 0=q 1=k 2=v (uniform over i)
    const int hd  = obase & 127;
    const int h   = hd >> 5;
    const int d0  = hd & 31;               // multiple of 4
    float* dst = (sel == 0) ? qt : (sel == 1) ? kt : vt;
    const float mul = (sel == 0) ? QK_SCALE : 1.0f;
    const size_t bh = (size_t)(b * NH + h);
#pragma unroll
    for (int j = 0; j < 4; ++j) {
        const int n = n0 + tn * 4 + j;
        float4 v4 = make_float4(acc[0][j] * mul, acc[1][j] * mul,
                                acc[2][j] * mul, acc[3][j] * mul);
        *(float4*)&dst[(bh * NN + n) * DH + d0] = v4;
    }
}

// ---------------------------------------------------------------------------
// Kernel 2: flash attention, one thread per query row.
// K/V rows are wave-uniform -> scalar loads (s_load) feed v_fmac; online
// softmax state (m,l) and O[32] live in registers; j processed in tiles of 16
// so the alpha-rescale of O amortizes.
// ---------------------------------------------------------------------------
__global__ __launch_bounds__(256) void attn_kernel(
    const float* __restrict__ qt, const float* __restrict__ kt,
    const float* __restrict__ vt, float* __restrict__ aout)
{
    const int bh = blockIdx.y;                       // 0..31
    const int i  = blockIdx.x * 256 + (int)threadIdx.x;  // query row
    const float* qrow = qt + ((size_t)bh * NN + i) * DH;
    const float* kb   = kt + (size_t)bh * NN * DH;
    const float* vb   = vt + (size_t)bh * NN * DH;

    float q[DH];
#pragma unroll
    for (int d = 0; d < DH; d += 4) {
        const float4 t = *(const float4*)(qrow + d);
        q[d] = t.x; q[d + 1] = t.y; q[d + 2] = t.z; q[d + 3] = t.w;
    }
    float m = -3.0e38f, l = 0.f;
    float O[DH];
#pragma unroll
    for (int d = 0; d < DH; ++d) O[d] = 0.f;

    for (int j0 = 0; j0 < NN; j0 += 16) {
        float s[16];
#pragma unroll
        for (int jj = 0; jj < 16; ++jj) {
            const float* kj = kb + (size_t)(j0 + jj) * DH;  // wave-uniform
            float a0 = 0.f, a1 = 0.f, a2 = 0.f, a3 = 0.f;
#pragma unroll
            for (int d = 0; d < DH; d += 4) {
                a0 += q[d]     * kj[d];
                a1 += q[d + 1] * kj[d + 1];
                a2 += q[d + 2] * kj[d + 2];
                a3 += q[d + 3] * kj[d + 3];
            }
            s[jj] = (a0 + a1) + (a2 + a3);
        }
        float mt = s[0];
#pragma unroll
        for (int jj = 1; jj < 16; ++jj) mt = fmaxf(mt, s[jj]);
        const float mn = fmaxf(m, mt);
        const float alpha = __expf(m - mn);
        float p[16];
        float ls = 0.f;
#pragma unroll
        for (int jj = 0; jj < 16; ++jj) { p[jj] = __expf(s[jj] - mn); ls += p[jj]; }
        l = l * alpha + ls;
#pragma unroll
        for (int d = 0; d < DH; ++d) O[d] *= alpha;
#pragma unroll
        for (int jj = 0; jj < 16; ++jj) {
            const float* vj = vb + (size_t)(j0 + jj) * DH;  // wave-uniform
#pragma unroll
            for (int d = 0; d < DH; ++d) O[d] += p[jj] * vj[d];
        }
        m = mn;
    }
    const float inv = 1.0f / l;
    // aout[b][c][n] with c = bh*32 + d ; lanes (i) consecutive -> coalesced
    float* ob = aout + (size_t)bh * DH * NN + i;
#pragma unroll
    for (int d = 0; d < DH; ++d) ob[(size_t)d * NN] = O[d] * inv;
}

// ---------------------------------------------------------------------------
// Kernel 3: output projection + bias.
// y[b][o][n] = sum_c w_out[o][c] * aout[b][c][n] + b_out[o]
// ---------------------------------------------------------------------------
__global__ __launch_bounds__(256) void out_proj_kernel(
    const float* __restrict__ a, const float* __restrict__ w,
    const float* __restrict__ bias, float* __restrict__ y)
{
    __shared__ float Ws[16][68];
    __shared__ float Xs[16][68];
    const int n0 = blockIdx.x * 64;
    const int o0 = blockIdx.y * 64;
    const int b  = blockIdx.z;
    const int tid = (int)threadIdx.x;
    const int tm = tid >> 4;
    const int tn = tid & 15;
    const float* ab = a + (size_t)b * HIDC * NN;

    float acc[4][4];
#pragma unroll
    for (int i = 0; i < 4; ++i)
#pragma unroll
        for (int j = 0; j < 4; ++j) acc[i][j] = 0.f;

    const int lo  = tid >> 4;
    const int lk  = tid & 15;
    const int xn  = tid & 63;
    const int xk4 = (tid >> 6) * 4;

    for (int k0 = 0; k0 < HIDC; k0 += 16) {
#pragma unroll
        for (int r = 0; r < 4; ++r) {
            const int o = lo + 16 * r;
            Ws[lk][o] = w[(size_t)(o0 + o) * HIDC + (k0 + lk)];
        }
#pragma unroll
        for (int r = 0; r < 4; ++r) {
            const int k = xk4 + r;
            Xs[k][xn] = ab[(size_t)(k0 + k) * NN + (n0 + xn)];
        }
        __syncthreads();
#pragma unroll
        for (int k = 0; k < 16; ++k) {
            const float4 av = *(const float4*)&Ws[k][tm * 4];
            const float4 bv = *(const float4*)&Xs[k][tn * 4];
            const float aa[4] = {av.x, av.y, av.z, av.w};
            const float bb[4] = {bv.x, bv.y, bv.z, bv.w};
#pragma unroll
            for (int i = 0; i < 4; ++i)
#pragma unroll
                for (int j = 0; j < 4; ++j)
                    acc[i][j] += aa[i] * bb[j];
        }
        __syncthreads();
    }

    const int ob0 = o0 + tm * 4;
#pragma unroll
    for (int i = 0; i < 4; ++i) {
        const int o = ob0 + i;
        const float bo = bias[o];
        float* yrow = y + ((size_t)(b * CDIM + o)) * NN;
        float4 v4 = make_float4(acc[i][0] + bo, acc[i][1] + bo,
                                acc[i][2] + bo, acc[i][3] + bo);
        *(float4*)&yrow[n0 + tn * 4] = v4;
    }
}

// ---------------------------------------------------------------------------
extern "C" void kernel_launch(void* const* d_in, const int* in_sizes, int n_in,
                              void* d_out, int out_size, void* d_ws, size_t ws_size,
                              hipStream_t stream)
{
    (void)in_sizes; (void)n_in; (void)out_size; (void)ws_size;
    const float* x     = (const float*)d_in[0];
    const float* w_qkv = (const float*)d_in[1];
    const float* w_out = (const float*)d_in[2];
    const float* b_out = (const float*)d_in[3];
    float* y = (float*)d_out;

    const size_t SEG = (size_t)NB * NH * NN * DH;   // 2,359,296 floats
    float* qt = (float*)d_ws;
    float* kt = qt + SEG;
    float* vt = kt + SEG;
    float* ao = vt + SEG;                            // [b][c=128][n]

    dim3 g1(NN / 64, OC3 / 64, NB);                  // 36 x 6 x 8
    qkv_proj_kernel<<<g1, 256, 0, stream>>>(x, w_qkv, qt, kt, vt);

    dim3 g2(NN / 256, NB * NH);                      // 9 x 32
    attn_kernel<<<g2, 256, 0, stream>>>(qt, kt, vt, ao);

    dim3 g3(NN / 64, CDIM / 64, NB);                 // 36 x 4 x 8
    out_proj_kernel<<<g3, 256, 0, stream>>>(ao, w_out, b_out, y);
}

// Round 2
// 267.268 us; speedup vs baseline: 9.7216x; 9.7216x over previous
//
#include <hip/hip_runtime.h>
#include <math.h>

#define NB    8
#define CDIM  256
#define NN    2304
#define NH    4
#define DH    32
#define HIDC  128
#define OC3   384
#define QK_SCALE 0.17677669529663687f   // 32^-0.5

typedef short  bf16x8 __attribute__((ext_vector_type(8)));
typedef float  f32x4  __attribute__((ext_vector_type(4)));

__device__ __forceinline__ unsigned short f2bf(float f) {
    union { float f; unsigned u; } a; a.f = f;
    unsigned r = a.u + 0x7fffu + ((a.u >> 16) & 1u);   // RNE
    return (unsigned short)(r >> 16);
}

// ---------------------------------------------------------------------------
// Kernel 1: QKV projection (fp32 GEMM), epilogue converts to bf16.
//   qt, kt : [bh][n][d=32] bf16 rows (q pre-scaled by QK_SCALE)
//   vtT    : [bh][d=32][n] bf16 (transposed, so attention reads Vt rows b128)
// ---------------------------------------------------------------------------
__global__ __launch_bounds__(256) void qkv_proj_kernel(
    const float* __restrict__ x, const float* __restrict__ w,
    unsigned short* __restrict__ qt, unsigned short* __restrict__ kt,
    unsigned short* __restrict__ vtT)
{
    __shared__ float Ws[16][68];
    __shared__ float Xs[16][68];
    const int n0 = blockIdx.x * 64;
    const int o0 = blockIdx.y * 64;
    const int b  = blockIdx.z;
    const int tid = (int)threadIdx.x;
    const int tm = tid >> 4;
    const int tn = tid & 15;
    const float* xb = x + (size_t)b * CDIM * NN;

    float acc[4][4];
#pragma unroll
    for (int i = 0; i < 4; ++i)
#pragma unroll
        for (int j = 0; j < 4; ++j) acc[i][j] = 0.f;

    const int lo  = tid >> 4;
    const int lk  = tid & 15;
    const int xn  = tid & 63;
    const int xk4 = (tid >> 6) * 4;

    for (int k0 = 0; k0 < CDIM; k0 += 16) {
#pragma unroll
        for (int r = 0; r < 4; ++r) {
            const int o = lo + 16 * r;
            Ws[lk][o] = w[(size_t)(o0 + o) * CDIM + (k0 + lk)];
        }
#pragma unroll
        for (int r = 0; r < 4; ++r) {
            const int k = xk4 + r;
            Xs[k][xn] = xb[(size_t)(k0 + k) * NN + (n0 + xn)];
        }
        __syncthreads();
#pragma unroll
        for (int k = 0; k < 16; ++k) {
            const float4 av = *(const float4*)&Ws[k][tm * 4];
            const float4 bv = *(const float4*)&Xs[k][tn * 4];
            const float a[4]  = {av.x, av.y, av.z, av.w};
            const float bb[4] = {bv.x, bv.y, bv.z, bv.w};
#pragma unroll
            for (int i = 0; i < 4; ++i)
#pragma unroll
                for (int j = 0; j < 4; ++j)
                    acc[i][j] += a[i] * bb[j];
        }
        __syncthreads();
    }

    const int obase = o0 + tm * 4;          // 4 consecutive o = 4 consecutive d
    const int sel = obase >> 7;             // 0=q 1=k 2=v
    const int hd  = obase & 127;
    const int h   = hd >> 5;
    const int d0  = hd & 31;                // multiple of 4
    const size_t bh = (size_t)(b * NH + h);

    if (sel == 2) {
        // transposed store: vtT[bh][d0+i][n0+tn*4+j]
#pragma unroll
        for (int i = 0; i < 4; ++i) {
            unsigned lo32 = (unsigned)f2bf(acc[i][0]) | ((unsigned)f2bf(acc[i][1]) << 16);
            unsigned hi32 = (unsigned)f2bf(acc[i][2]) | ((unsigned)f2bf(acc[i][3]) << 16);
            uint2 pk; pk.x = lo32; pk.y = hi32;
            *(uint2*)&vtT[(bh * DH + d0 + i) * (size_t)NN + n0 + tn * 4] = pk;
        }
    } else {
        unsigned short* dst = (sel == 0) ? qt : kt;
        const float mul = (sel == 0) ? QK_SCALE : 1.0f;
#pragma unroll
        for (int j = 0; j < 4; ++j) {
            const int n = n0 + tn * 4 + j;
            unsigned lo32 = (unsigned)f2bf(acc[0][j] * mul) | ((unsigned)f2bf(acc[1][j] * mul) << 16);
            unsigned hi32 = (unsigned)f2bf(acc[2][j] * mul) | ((unsigned)f2bf(acc[3][j] * mul) << 16);
            uint2 pk; pk.x = lo32; pk.y = hi32;
            *(uint2*)&dst[((size_t)bh * NN + n) * DH + d0] = pk;
        }
    }
}

// ---------------------------------------------------------------------------
// Kernel 2: MFMA flash attention. One wave = 16 queries; sweeps all j in
// chunks of 32. S^T = K·Q^T (both operands contiguous b128 frags); softmax
// state per-lane scalar (i = lane&15); PV as O^T = V^T·P^T with P^T passed
// through a wave-private LDS transpose (no barrier needed).
// ---------------------------------------------------------------------------
__global__ __launch_bounds__(256) void attn_kernel(
    const unsigned short* __restrict__ qt, const unsigned short* __restrict__ kt,
    const unsigned short* __restrict__ vtT, float* __restrict__ aout)
{
    __shared__ unsigned short Pl[4][16 * 40];   // per-wave, row stride 40 (80 B, 16B-aligned)
    const int bh   = blockIdx.y;
    const int tid  = (int)threadIdx.x;
    const int wave = tid >> 6;
    const int lane = tid & 63;
    const int li   = lane & 15;     // i (or m) index
    const int g    = lane >> 4;     // 4-lane-group 0..3
    const int i0   = blockIdx.x * 64 + wave * 16;

    const unsigned short* qb = qt  + (size_t)bh * NN * DH;
    const unsigned short* kb = kt  + (size_t)bh * NN * DH;
    const unsigned short* vb = vtT + (size_t)bh * DH * NN;

    // Q B-frag: lane holds i=li, d = g*8..g*8+7 (loaded once)
    bf16x8 qf = *(const bf16x8*)(qb + (size_t)(i0 + li) * DH + g * 8);

    f32x4 O0 = {0.f, 0.f, 0.f, 0.f};   // O^T rows d = 4g+r,     col i = li
    f32x4 O1 = {0.f, 0.f, 0.f, 0.f};   // O^T rows d = 16+4g+r
    float m = -3.0e38f, l = 0.f;
    unsigned short* pl = &Pl[wave][0];

    for (int j0 = 0; j0 < NN; j0 += 32) {
        // K A-frags: lane holds j-row = j0(+16)+li, d = g*8..+7
        bf16x8 kf0 = *(const bf16x8*)(kb + (size_t)(j0 +      li) * DH + g * 8);
        bf16x8 kf1 = *(const bf16x8*)(kb + (size_t)(j0 + 16 + li) * DH + g * 8);
        // V^T A-frags: lane holds d-row = li (+16), j = j0 + g*8..+7
        bf16x8 vf0 = *(const bf16x8*)(vb + (size_t)(li)      * NN + j0 + g * 8);
        bf16x8 vf1 = *(const bf16x8*)(vb + (size_t)(16 + li) * NN + j0 + g * 8);

        f32x4 z = {0.f, 0.f, 0.f, 0.f};
        // S^T tiles: col i = li, rows j_local = 16t + 4g + r
        f32x4 s0 = __builtin_amdgcn_mfma_f32_16x16x32_bf16(kf0, qf, z, 0, 0, 0);
        f32x4 s1 = __builtin_amdgcn_mfma_f32_16x16x32_bf16(kf1, qf, z, 0, 0, 0);

        float cmax = fmaxf(fmaxf(fmaxf(s0[0], s0[1]), fmaxf(s0[2], s0[3])),
                           fmaxf(fmaxf(s1[0], s1[1]), fmaxf(s1[2], s1[3])));
        cmax = fmaxf(cmax, __shfl_xor(cmax, 16, 64));
        cmax = fmaxf(cmax, __shfl_xor(cmax, 32, 64));
        const float mn = fmaxf(m, cmax);
        const float alpha = __expf(m - mn);
        m = mn;

        float p0[4], p1[4];
        float rs = 0.f;
#pragma unroll
        for (int r = 0; r < 4; ++r) { p0[r] = __expf(s0[r] - mn); rs += p0[r]; }
#pragma unroll
        for (int r = 0; r < 4; ++r) { p1[r] = __expf(s1[r] - mn); rs += p1[r]; }
        rs += __shfl_xor(rs, 16, 64);
        rs += __shfl_xor(rs, 32, 64);
        l = l * alpha + rs;

        // P^T transpose through wave-private LDS: write Pl[i=li][j_local]
        unsigned w0 = (unsigned)f2bf(p0[0]) | ((unsigned)f2bf(p0[1]) << 16);
        unsigned w1 = (unsigned)f2bf(p0[2]) | ((unsigned)f2bf(p0[3]) << 16);
        unsigned w2 = (unsigned)f2bf(p1[0]) | ((unsigned)f2bf(p1[1]) << 16);
        unsigned w3 = (unsigned)f2bf(p1[2]) | ((unsigned)f2bf(p1[3]) << 16);
        *(unsigned*)&pl[li * 40 + 4 * g]          = w0;   // j = 4g,4g+1
        *(unsigned*)&pl[li * 40 + 4 * g + 2]      = w1;   // j = 4g+2,4g+3
        *(unsigned*)&pl[li * 40 + 16 + 4 * g]     = w2;   // j = 16+4g..
        *(unsigned*)&pl[li * 40 + 16 + 4 * g + 2] = w3;

        // B-frag read: lane holds col i=li, k=j = g*8..g*8+7 (b128)
        bf16x8 pf = *(bf16x8*)&pl[li * 40 + g * 8];

#pragma unroll
        for (int r = 0; r < 4; ++r) { O0[r] *= alpha; O1[r] *= alpha; }
        O0 = __builtin_amdgcn_mfma_f32_16x16x32_bf16(vf0, pf, O0, 0, 0, 0);
        O1 = __builtin_amdgcn_mfma_f32_16x16x32_bf16(vf1, pf, O1, 0, 0, 0);
    }

    const float inv = 1.0f / l;
    // O^T[d][i] -> aout[b][c = h*32+d][n = i]
    float* ob = aout + (size_t)bh * DH * NN + i0 + li;
#pragma unroll
    for (int r = 0; r < 4; ++r) {
        ob[(size_t)(4 * g + r)      * NN] = O0[r] * inv;
        ob[(size_t)(16 + 4 * g + r) * NN] = O1[r] * inv;
    }
}

// ---------------------------------------------------------------------------
// Kernel 3: output projection + bias (unchanged fp32 GEMM).
// ---------------------------------------------------------------------------
__global__ __launch_bounds__(256) void out_proj_kernel(
    const float* __restrict__ a, const float* __restrict__ w,
    const float* __restrict__ bias, float* __restrict__ y)
{
    __shared__ float Ws[16][68];
    __shared__ float Xs[16][68];
    const int n0 = blockIdx.x * 64;
    const int o0 = blockIdx.y * 64;
    const int b  = blockIdx.z;
    const int tid = (int)threadIdx.x;
    const int tm = tid >> 4;
    const int tn = tid & 15;
    const float* ab = a + (size_t)b * HIDC * NN;

    float acc[4][4];
#pragma unroll
    for (int i = 0; i < 4; ++i)
#pragma unroll
        for (int j = 0; j < 4; ++j) acc[i][j] = 0.f;

    const int lo  = tid >> 4;
    const int lk  = tid & 15;
    const int xn  = tid & 63;
    const int xk4 = (tid >> 6) * 4;

    for (int k0 = 0; k0 < HIDC; k0 += 16) {
#pragma unroll
        for (int r = 0; r < 4; ++r) {
            const int o = lo + 16 * r;
            Ws[lk][o] = w[(size_t)(o0 + o) * HIDC + (k0 + lk)];
        }
#pragma unroll
        for (int r = 0; r < 4; ++r) {
            const int k = xk4 + r;
            Xs[k][xn] = ab[(size_t)(k0 + k) * NN + (n0 + xn)];
        }
        __syncthreads();
#pragma unroll
        for (int k = 0; k < 16; ++k) {
            const float4 av = *(const float4*)&Ws[k][tm * 4];
            const float4 bv = *(const float4*)&Xs[k][tn * 4];
            const float aa[4] = {av.x, av.y, av.z, av.w};
            const float bb[4] = {bv.x, bv.y, bv.z, bv.w};
#pragma unroll
            for (int i = 0; i < 4; ++i)
#pragma unroll
                for (int j = 0; j < 4; ++j)
                    acc[i][j] += aa[i] * bb[j];
        }
        __syncthreads();
    }

    const int ob0 = o0 + tm * 4;
#pragma unroll
    for (int i = 0; i < 4; ++i) {
        const int o = ob0 + i;
        const float bo = bias[o];
        float* yrow = y + ((size_t)(b * CDIM + o)) * NN;
        float4 v4 = make_float4(acc[i][0] + bo, acc[i][1] + bo,
                                acc[i][2] + bo, acc[i][3] + bo);
        *(float4*)&yrow[n0 + tn * 4] = v4;
    }
}

// ---------------------------------------------------------------------------
extern "C" void kernel_launch(void* const* d_in, const int* in_sizes, int n_in,
                              void* d_out, int out_size, void* d_ws, size_t ws_size,
                              hipStream_t stream)
{
    (void)in_sizes; (void)n_in; (void)out_size; (void)ws_size;
    const float* x     = (const float*)d_in[0];
    const float* w_qkv = (const float*)d_in[1];
    const float* w_out = (const float*)d_in[2];
    const float* b_out = (const float*)d_in[3];
    float* y = (float*)d_out;

    const size_t SEG = (size_t)NB * NH * NN * DH;      // 2,359,296 elements
    unsigned short* qt  = (unsigned short*)d_ws;
    unsigned short* kt  = qt + SEG;
    unsigned short* vtT = kt + SEG;
    float*          ao  = (float*)(vtT + SEG);          // [b][c=128][n] fp32

    dim3 g1(NN / 64, OC3 / 64, NB);                     // 36 x 6 x 8
    qkv_proj_kernel<<<g1, 256, 0, stream>>>(x, w_qkv, qt, kt, vtT);

    dim3 g2(NN / 64, NB * NH);                          // 36 x 32
    attn_kernel<<<g2, 256, 0, stream>>>(qt, kt, vtT, ao);

    dim3 g3(NN / 64, CDIM / 64, NB);                    // 36 x 4 x 8
    out_proj_kernel<<<g3, 256, 0, stream>>>(ao, w_out, b_out, y);
}